// Round 8
// baseline (349.484 us; speedup 1.0000x reference)
//
#include <hip/hip_runtime.h>

// B=4, N=4096, E=2048, C=64.  H is binary (5% dense) -> bit-pack + SPARSE
// scalar-driven accumulation (no MFMA: dense GEMM was VALU-bound on bit
// expansion; useful FLOPs are only ~0.9 GF).
//  k_transform: xt[b][n][o] fp32 (4 MB), plain matmul vs theta.
//  k_prep:      read H fp32 once (134 MB = traffic floor), emit
//               Hbits[b][n][32 u64] and HbitsT[b][e][64 u64] via ballot
//               bit-transpose. No degrees (popcount at use site).
//  k_edge:      per (b,e) wave: scan set n-bits (scalar ffs, 4-way ILP),
//               acc[o] += xt[n][o]; he[e][o] = acc/popcount. fp32 exact.
//  k_node:      per (b,n) wave: scan set e-bits, acc[o] += he[e][o];
//               out[n][o] = acc/popcount + bias[o].
#define B_ 4
#define N_ 4096
#define E_ 2048

// ---------------------------------------------------------------------------
// K1: xt[bn][o] = sum_k x[bn][k] * theta[k][o]   (row-major fp32)
// ---------------------------------------------------------------------------
__global__ __launch_bounds__(256) void k_transform(
    const float* __restrict__ x, const float* __restrict__ theta,
    float* __restrict__ xt) {
  int idx = blockIdx.x * 256 + threadIdx.x;  // [0, B*N*64)
  int o = idx & 63, bn = idx >> 6;
  const float* xr = x + ((size_t)bn << 6);
  float acc = 0.f;
#pragma unroll
  for (int k = 0; k < 64; ++k) acc += xr[k] * theta[k * 64 + o];
  xt[idx] = acc;
}

// ---------------------------------------------------------------------------
// K2: bit-pack H both orientations. grid 1024 = et(4) x nt(64) x b(4).
// Phase 1: loads hoisted (32 per drain) then ballots -> n-major words in LDS.
// Phase 2: ballot 64x64 bit-transpose -> HbitsT (e-major words).
// Phase 3: coalesced copy-out -> Hbits (n-major words).
// ---------------------------------------------------------------------------
__global__ __launch_bounds__(256) void k_prep(
    const float* __restrict__ H, unsigned long long* __restrict__ Hbits,
    unsigned long long* __restrict__ HbitsT) {
  __shared__ unsigned long long ldsBits[64][9];  // [n_local][e_word], padded
  int t = threadIdx.x;
  int et = blockIdx.x & 3, nt = (blockIdx.x >> 2) & 63, b = blockIdx.x >> 8;
  int e0 = et * 512, n0 = nt * 64;
  int w = t >> 6, lane = t & 63;

  const float* src = H + ((size_t)(b * N_ + n0 + w * 16)) * E_ + e0 + lane;
  for (int r4 = 0; r4 < 4; ++r4) {
    float v[4][8];
#pragma unroll
    for (int r = 0; r < 4; ++r)
#pragma unroll
      for (int wd = 0; wd < 8; ++wd)
        v[r][wd] = src[(size_t)(r4 * 4 + r) * E_ + wd * 64];
#pragma unroll
    for (int r = 0; r < 4; ++r) {
      int row = w * 16 + r4 * 4 + r;
#pragma unroll
      for (int wd = 0; wd < 8; ++wd) {
        unsigned long long m = __ballot(v[r][wd] != 0.0f);
        if (lane == 0) ldsBits[row][wd] = m;
      }
    }
  }
  __syncthreads();
  // phase 2: wave w transposes e-words 2w, 2w+1 (64 e each)
#pragma unroll
  for (int p = 0; p < 2; ++p) {
    int wd = w * 2 + p;
    unsigned long long col = ldsBits[lane][wd];  // lane = n_local
    unsigned long long mine = 0;
#pragma unroll
    for (int bit = 0; bit < 64; ++bit) {
      unsigned long long m = __ballot((col >> bit) & 1ull);  // bit i = n0+i
      if (lane == bit) mine = m;
    }
    int e = e0 + wd * 64 + lane;
    HbitsT[(((size_t)(b * E_ + e)) << 6) + nt] = mine;
  }
  // phase 3: copy n-major words out
  int i = t * 2;
  int row = i >> 3, wd2 = i & 7;
  unsigned long long* dst =
      Hbits + (((size_t)(b * N_ + n0 + row)) << 5) + et * 8 + wd2;
  dst[0] = ldsBits[row][wd2];
  dst[1] = ldsBits[row][wd2 + 1];
}

// ---------------------------------------------------------------------------
// K3 (sparse edge aggregation): wave = one (b,e); lane = channel o.
//   he[b][e][o] = ( sum_{n: H[n][e]=1} xt[b][n][o] ) / deg_e
// Scalar (wave-uniform) bit words; 4-word interleave -> ~3-4 loads in flight.
// grid 2048 blocks x 4 waves.
// ---------------------------------------------------------------------------
__global__ __launch_bounds__(256) void k_edge(
    const unsigned long long* __restrict__ HbitsT,
    const float* __restrict__ xt, float* __restrict__ he) {
  int w = threadIdx.x >> 6, lane = threadIdx.x & 63;
  int be = __builtin_amdgcn_readfirstlane(blockIdx.x * 4 + w);  // b*E + e
  int b = be >> 11;
  const unsigned long long* row = HbitsT + ((size_t)be << 6);
  const float* xb = xt + (((size_t)b * N_) << 6);
  float a0 = 0.f, a1 = 0.f, a2 = 0.f, a3 = 0.f;
  int cnt = 0;
  for (int wd = 0; wd < 64; wd += 4) {
    unsigned long long w0 = row[wd], w1 = row[wd + 1], w2 = row[wd + 2],
                       w3 = row[wd + 3];
    cnt += __popcll(w0) + __popcll(w1) + __popcll(w2) + __popcll(w3);
    int nb0 = wd << 6, nb1 = nb0 + 64, nb2 = nb0 + 128, nb3 = nb0 + 192;
    while (w0 | w1 | w2 | w3) {
      if (w0) {
        int n = nb0 + __builtin_ctzll(w0); w0 &= w0 - 1;
        a0 += xb[((size_t)n << 6) + lane];
      }
      if (w1) {
        int n = nb1 + __builtin_ctzll(w1); w1 &= w1 - 1;
        a1 += xb[((size_t)n << 6) + lane];
      }
      if (w2) {
        int n = nb2 + __builtin_ctzll(w2); w2 &= w2 - 1;
        a2 += xb[((size_t)n << 6) + lane];
      }
      if (w3) {
        int n = nb3 + __builtin_ctzll(w3); w3 &= w3 - 1;
        a3 += xb[((size_t)n << 6) + lane];
      }
    }
  }
  float s = (a0 + a1) + (a2 + a3);
  he[((size_t)be << 6) + lane] = s / (float)cnt;
}

// ---------------------------------------------------------------------------
// K4 (sparse node aggregation): wave = one (b,n); lane = channel o.
//   out[b][n][o] = ( sum_{e: H[n][e]=1} he[b][e][o] ) / deg_n + bias[o]
// grid 4096 blocks x 4 waves.
// ---------------------------------------------------------------------------
__global__ __launch_bounds__(256) void k_node(
    const unsigned long long* __restrict__ Hbits,
    const float* __restrict__ he, const float* __restrict__ bias,
    float* __restrict__ out) {
  int w = threadIdx.x >> 6, lane = threadIdx.x & 63;
  int bn = __builtin_amdgcn_readfirstlane(blockIdx.x * 4 + w);  // b*N + n
  int b = bn >> 12;
  const unsigned long long* row = Hbits + ((size_t)bn << 5);
  const float* hb = he + (((size_t)b * E_) << 6);
  float a0 = 0.f, a1 = 0.f, a2 = 0.f, a3 = 0.f;
  int cnt = 0;
  for (int wd = 0; wd < 32; wd += 4) {
    unsigned long long w0 = row[wd], w1 = row[wd + 1], w2 = row[wd + 2],
                       w3 = row[wd + 3];
    cnt += __popcll(w0) + __popcll(w1) + __popcll(w2) + __popcll(w3);
    int eb0 = wd << 6, eb1 = eb0 + 64, eb2 = eb0 + 128, eb3 = eb0 + 192;
    while (w0 | w1 | w2 | w3) {
      if (w0) {
        int e = eb0 + __builtin_ctzll(w0); w0 &= w0 - 1;
        a0 += hb[((size_t)e << 6) + lane];
      }
      if (w1) {
        int e = eb1 + __builtin_ctzll(w1); w1 &= w1 - 1;
        a1 += hb[((size_t)e << 6) + lane];
      }
      if (w2) {
        int e = eb2 + __builtin_ctzll(w2); w2 &= w2 - 1;
        a2 += hb[((size_t)e << 6) + lane];
      }
      if (w3) {
        int e = eb3 + __builtin_ctzll(w3); w3 &= w3 - 1;
        a3 += hb[((size_t)e << 6) + lane];
      }
    }
  }
  float s = (a0 + a1) + (a2 + a3);
  out[((size_t)bn << 6) + lane] = s / (float)cnt + bias[lane];
}

extern "C" void kernel_launch(void* const* d_in, const int* in_sizes, int n_in,
                              void* d_out, int out_size, void* d_ws, size_t ws_size,
                              hipStream_t stream) {
  const float* x     = (const float*)d_in[0];
  const float* H     = (const float*)d_in[1];
  const float* theta = (const float*)d_in[2];
  const float* bias  = (const float*)d_in[3];

  // ws (bytes): xt 4MB | Hbits 4MB | HbitsT 4MB | he 2MB   (14 MB total)
  char* ws = (char*)d_ws;
  float* xt                  = (float*)ws;
  unsigned long long* Hbits  = (unsigned long long*)(ws + 4194304);
  unsigned long long* HbitsT = (unsigned long long*)(ws + 8388608);
  float* he                  = (float*)(ws + 12582912);

  k_transform<<<(B_ * N_ * 64) / 256, 256, 0, stream>>>(x, theta, xt);
  k_prep<<<1024, 256, 0, stream>>>(H, Hbits, HbitsT);
  k_edge<<<(B_ * E_) / 4, 256, 0, stream>>>(HbitsT, xt, he);
  k_node<<<(B_ * N_) / 4, 256, 0, stream>>>(Hbits, he, bias, (float*)d_out);
}

// Round 9
// 241.762 us; speedup vs baseline: 1.4456x; 1.4456x over previous
//
#include <hip/hip_runtime.h>

// B=4, N=4096, E=2048, C=64.  Single fp32 pass over H (fused into the edge
// GEMM, which also emits bit-packed H), then a bit-driven node GEMM.
//  k_transform: xtT[b][o][n] bf16 (2 MB)
//  k_edge:  p_he[ks] += xtT * H  (fused fp32->bf16 transpose via LDS) AND
//           Hbits[b][wd][n] (word-major, 4 MB) via __ballot AND deg_e_part.
//           K-split x4 over N. This is the ONLY reader of fp32 H (134 MB).
//  k_henorm: combine/deg_e -> heT bf16 (1 MB)
//  k_node:  q[ks] = H * heT with A = Hbits u64 (L2-hot) expanded in regs,
//           B = heT staged via global_load_lds; deg_n via popcount. x4 split.
//  k_final: combine/deg_n + bias.
#define B_ 4
#define N_ 4096
#define E_ 2048

typedef __attribute__((ext_vector_type(8))) short short8;   // 8 bf16
typedef __attribute__((ext_vector_type(4))) float float4v;  // MFMA C/D

// round-to-nearest-even f32 -> bf16 bits
static __device__ __forceinline__ unsigned short f2bf(float f) {
  union { float f; unsigned int u; } v; v.f = f;
  unsigned int r = (v.u + 0x7FFFu + ((v.u >> 16) & 1u)) >> 16;
  return (unsigned short)r;
}

// expand 8 H-bits -> 8 bf16 values {0.0, 1.0}
static __device__ __forceinline__ short8 expand8(unsigned int by) {
  short8 r;
#pragma unroll
  for (int j = 0; j < 8; ++j)
    r[j] = (short)(((by >> j) & 1u) ? 0x3F80 : 0);
  return r;
}

static __device__ __forceinline__ void stage16(const void* g, void* l) {
  __builtin_amdgcn_global_load_lds(
      (const __attribute__((address_space(1))) unsigned int*)g,
      (__attribute__((address_space(3))) unsigned int*)l, 16, 0, 0);
}

// ---------------------------------------------------------------------------
// K1: xtT[b][o][n] = bf16( sum_k x[b][n][k] * theta[k][o] )   (transposed)
// ---------------------------------------------------------------------------
__global__ __launch_bounds__(256) void k_transform(
    const float* __restrict__ x, const float* __restrict__ theta,
    unsigned short* __restrict__ xtT) {
  __shared__ unsigned short ldsT[64][72];
  int t = threadIdx.x;
  int nt = blockIdx.x & 63, b = blockIdx.x >> 6;
  int n0 = nt * 64;
  int o = t & 63, nq = t >> 6;
#pragma unroll 4
  for (int i = 0; i < 16; ++i) {
    int n = n0 + nq * 16 + i;
    const float* xr = x + ((size_t)(b * N_ + n) << 6);
    float acc = 0.f;
#pragma unroll
    for (int k = 0; k < 64; ++k) acc += xr[k] * theta[k * 64 + o];
    ldsT[o][nq * 16 + i] = f2bf(acc);
  }
  __syncthreads();
  int orow = t >> 2, c = (t & 3) * 16;
  unsigned short* dst = xtT + ((size_t)(b * 64 + orow) << 12) + n0 + c;
  *(uint4*)dst = *(const uint4*)&ldsT[orow][c];
  *(uint4*)(dst + 8) = *(const uint4*)&ldsT[orow][c + 8];
}

// ---------------------------------------------------------------------------
// K2 (fused edge GEMM + bit-pack): for K-chunk ks (1024 n each, x4):
//   p_he[ks][b][o][e]   = sum_{n chunk} xtT[o][n] * H[n][e]
//   deg_e_part[ks][b][e] = sum_{n chunk} H[n][e]
//   Hbits[b][et][n chunk] = ballot-packed bits (word-major: coalesced write
//                            here, coalesced read in k_node)
// grid 512 = ks(4) x et(32) x b(4); block 64o x 64e, BK=64, 16 iters.
// ---------------------------------------------------------------------------
__global__ __launch_bounds__(256) void k_edge(
    const unsigned short* __restrict__ xtT, const float* __restrict__ H,
    float* __restrict__ p_he, float* __restrict__ deg_e_part,
    unsigned long long* __restrict__ Hbits) {
  __shared__ unsigned short ldsA[4096];     // [o-row][k=n] 64x64, swizzled
  __shared__ unsigned short ldsB[64 * 72];  // [e-row][n] 64x72 padded
  __shared__ float ldsDe[64];
  __shared__ unsigned long long ldsW[1024];  // packed words for this n-chunk
  int t = threadIdx.x;
  int ks = blockIdx.x & 3, et = (blockIdx.x >> 2) & 31, b = blockIdx.x >> 7;
  int e0 = et * 64;
  int w = t >> 6, lane = t & 63, quad = lane >> 4, m15 = lane & 15;
  if (t < 64) ldsDe[t] = 0.f;

  int i0 = w * 128 + lane, i1 = i0 + 64;
  int row0 = i0 >> 3, cc0 = (i0 & 7) ^ (row0 & 7);
  int row1 = i1 >> 3, cc1 = (i1 & 7) ^ (row1 & 7);
  int gOff0 = row0 * 4096 + cc0 * 8;
  int gOff1 = row1 * 4096 + cc1 * 8;
  char* lA = (char*)ldsA; char* lB = (char*)ldsB;
  int lOff0 = i0 * 16, lOff1 = i1 * 16;

  const unsigned short* gA = xtT + ((size_t)b << 18) + ks * 1024;
  const float* gH = H + ((size_t)(b * N_ + ks * 1024 + w * 16)) * E_ + e0 + lane;

  int xr = m15 & 7;
  int aBase = (w * 16 + m15) * 128;
  int fs0 = (quad ^ xr) * 16, fs1 = ((4 + quad) ^ xr) * 16;
  int bw = lane * 144 + w * 32;

  float de = 0.f;
  float4v acc[4];
#pragma unroll
  for (int ct = 0; ct < 4; ++ct) acc[ct] = (float4v){0.f, 0.f, 0.f, 0.f};

  for (int kt = 0; kt < 16; ++kt) {
    float hv[16];
#pragma unroll
    for (int i = 0; i < 16; ++i) hv[i] = gH[(size_t)i * E_];
    // bit-pack: lane = e offset -> one 64-bit word per n-row
#pragma unroll
    for (int i = 0; i < 16; ++i) {
      unsigned long long m = __ballot(hv[i] != 0.0f);
      if (lane == 0) ldsW[kt * 64 + w * 16 + i] = m;
    }
#pragma unroll
    for (int i = 0; i < 16; ++i) de += hv[i];
    short8 pa, pb;
#pragma unroll
    for (int i = 0; i < 8; ++i) pa[i] = (short)f2bf(hv[i]);
#pragma unroll
    for (int i = 0; i < 8; ++i) pb[i] = (short)f2bf(hv[8 + i]);
    *(short8*)(lB + bw) = pa;
    *(short8*)(lB + bw + 16) = pb;
    stage16(gA + gOff0, lA + lOff0);
    stage16(gA + gOff1, lA + lOff1);
    __syncthreads();
#pragma unroll
    for (int s = 0; s < 2; ++s) {
      int fo = s ? fs1 : fs0;
      short8 a = *(const short8*)(lA + aBase + fo);
#pragma unroll
      for (int ct = 0; ct < 4; ++ct) {
        short8 bb =
            *(const short8*)(lB + (ct * 16 + m15) * 144 + s * 64 + quad * 16);
        acc[ct] = __builtin_amdgcn_mfma_f32_16x16x32_bf16(a, bb, acc[ct], 0, 0, 0);
      }
    }
    __syncthreads();
    gA += 64;
    gH += (size_t)64 * E_;
  }
  atomicAdd(&ldsDe[lane], de);
  __syncthreads();
  if (t < 64) deg_e_part[ks * (B_ * E_) + b * E_ + e0 + t] = ldsDe[t];
  // coalesced Hbits write: [b][et][n], n-chunk = ks*1024..+1024 (8 KB/block)
  unsigned long long* wdst =
      Hbits + (((size_t)(b * 32 + et)) << 12) + ks * 1024 + t * 4;
  wdst[0] = ldsW[t * 4 + 0];
  wdst[1] = ldsW[t * 4 + 1];
  wdst[2] = ldsW[t * 4 + 2];
  wdst[3] = ldsW[t * 4 + 3];
  float* dst = p_he + (size_t)ks * (B_ * 64 * E_);
#pragma unroll
  for (int ct = 0; ct < 4; ++ct)
#pragma unroll
    for (int r = 0; r < 4; ++r) {
      int oo = w * 16 + quad * 4 + r;
      dst[((size_t)(b * 64 + oo)) * E_ + e0 + ct * 16 + m15] = acc[ct][r];
    }
}

// ---------------------------------------------------------------------------
// K3: heT[b][o][e] = bf16( (sum_ks p_he[ks]) / (sum_ks deg_e_part[ks]) )
// ---------------------------------------------------------------------------
__global__ __launch_bounds__(256) void k_henorm(
    const float* __restrict__ p_he, const float* __restrict__ deg_e_part,
    unsigned short* __restrict__ heT) {
  int idx = (blockIdx.x * 256 + threadIdx.x) * 4;  // over B*64*E = 524288
  int e = idx & (E_ - 1);
  int b = idx >> 17;
  float4 s = *(const float4*)(p_he + idx);
  float4 d = *(const float4*)(deg_e_part + b * E_ + e);
#pragma unroll
  for (int k = 1; k < 4; ++k) {
    float4 sk = *(const float4*)(p_he + (size_t)k * (B_ * 64 * E_) + idx);
    float4 dk = *(const float4*)(deg_e_part + k * (B_ * E_) + b * E_ + e);
    s.x += sk.x; s.y += sk.y; s.z += sk.z; s.w += sk.w;
    d.x += dk.x; d.y += dk.y; d.z += dk.z; d.w += dk.w;
  }
  unsigned int lo = (unsigned int)f2bf(s.x / d.x) |
                    ((unsigned int)f2bf(s.y / d.y) << 16);
  unsigned int hi = (unsigned int)f2bf(s.z / d.z) |
                    ((unsigned int)f2bf(s.w / d.w) << 16);
  uint2 u; u.x = lo; u.y = hi;
  *(uint2*)(heT + idx) = u;
}

// ---------------------------------------------------------------------------
// K4 (node GEMM): for K-chunk ks (512 e each, x4):
//   q[ks][b][n][o] = sum_{e chunk} H[n][e]*heT[o][e]
//   deg_n_part[ks][b][n] = popcount of the same bit-words
// grid 1024 = ks(4) x mt(64) x b(4); 64n x 64o, BK=64, 8 iters.
// A = Hbits[b][wd][n] u64 (L2-hot, coalesced per 16-lane group) + reg expand;
// B = heT staged via global_load_lds.
// ---------------------------------------------------------------------------
__global__ __launch_bounds__(256) void k_node(
    const unsigned long long* __restrict__ Hbits,
    const unsigned short* __restrict__ heT, float* __restrict__ q,
    float* __restrict__ deg_n_part) {
  __shared__ unsigned short ldsB[4096];  // [o-row][k=e] swizzled
  int t = threadIdx.x;
  int ks = blockIdx.x & 3, mt = (blockIdx.x >> 2) & 63, b = blockIdx.x >> 8;
  int n0 = mt * 64;
  int w = t >> 6, lane = t & 63, quad = lane >> 4, m15 = lane & 15;

  int i0 = w * 128 + lane, i1 = i0 + 64;
  int row0 = i0 >> 3, cc0 = (i0 & 7) ^ (row0 & 7);
  int row1 = i1 >> 3, cc1 = (i1 & 7) ^ (row1 & 7);
  int gOffB0 = row0 * 2048 + cc0 * 8, gOffB1 = row1 * 2048 + cc1 * 8;
  const unsigned short* gB = heT + ((size_t)b << 17) + ks * 512;
  char* lB = (char*)ldsB;
  int lOff0 = i0 * 16, lOff1 = i1 * 16;

  int nl = n0 + w * 16 + m15;
  const unsigned long long* gAb =
      Hbits + (((size_t)(b * 32 + ks * 8)) << 12) + nl;

  int xr = m15 & 7;
  int fs0 = (quad ^ xr) * 16, fs1 = ((4 + quad) ^ xr) * 16;

  float4v acc[4];
#pragma unroll
  for (int ct = 0; ct < 4; ++ct) acc[ct] = (float4v){0.f, 0.f, 0.f, 0.f};

  unsigned int dcnt = 0;
  unsigned long long ua = gAb[0];

  for (int kt = 0; kt < 8; ++kt) {
    stage16(gB + gOffB0, lB + lOff0);
    stage16(gB + gOffB1, lB + lOff1);
    __syncthreads();
    unsigned long long va = 0;
    if (kt < 7) va = gAb[(size_t)(kt + 1) * 4096];  // prefetch next word
    dcnt += (unsigned int)__popcll(ua);
#pragma unroll
    for (int s = 0; s < 2; ++s) {
      int fo = s ? fs1 : fs0;
      short8 a = expand8((unsigned int)(ua >> ((s * 4 + quad) << 3)) & 0xFFu);
#pragma unroll
      for (int ct = 0; ct < 4; ++ct) {
        short8 bb = *(const short8*)(lB + (ct * 16 + m15) * 128 + fo);
        acc[ct] = __builtin_amdgcn_mfma_f32_16x16x32_bf16(a, bb, acc[ct], 0, 0, 0);
      }
    }
    __syncthreads();
    if (kt < 7) ua = va;
    gB += 64;
  }
  if (quad == 0) deg_n_part[ks * (B_ * N_) + b * N_ + nl] = (float)dcnt;
  float* dst = q + (size_t)ks * ((size_t)B_ * N_ * 64);
#pragma unroll
  for (int r = 0; r < 4; ++r) {
    int row = w * 16 + quad * 4 + r;
    int nn = n0 + row;
#pragma unroll
    for (int ct = 0; ct < 4; ++ct)
      dst[(((size_t)(b * N_ + nn)) << 6) + ct * 16 + m15] = acc[ct][r];
  }
}

// ---------------------------------------------------------------------------
// K5: out[b][n][o] = (sum_ks q[ks]) / (sum_ks deg_n_part[ks]) + bias[o]
// ---------------------------------------------------------------------------
__global__ __launch_bounds__(256) void k_final(
    const float* __restrict__ q, const float* __restrict__ deg_n_part,
    const float* __restrict__ bias, float* __restrict__ out) {
  int idx = (blockIdx.x * 256 + threadIdx.x) * 4;  // over B*N*64 = 1048576
  int o = idx & 63;
  int bn = idx >> 6;
  float4 s = *(const float4*)(q + idx);
  float dn = deg_n_part[bn];
#pragma unroll
  for (int k = 1; k < 4; ++k) {
    float4 sk = *(const float4*)(q + (size_t)k * ((size_t)B_ * N_ * 64) + idx);
    s.x += sk.x; s.y += sk.y; s.z += sk.z; s.w += sk.w;
    dn += deg_n_part[k * (B_ * N_) + bn];
  }
  float4 bv = *(const float4*)(bias + o);
  float inv = 1.0f / dn;
  float4 r;
  r.x = s.x * inv + bv.x; r.y = s.y * inv + bv.y;
  r.z = s.z * inv + bv.z; r.w = s.w * inv + bv.w;
  *(float4*)(out + idx) = r;
}

extern "C" void kernel_launch(void* const* d_in, const int* in_sizes, int n_in,
                              void* d_out, int out_size, void* d_ws, size_t ws_size,
                              hipStream_t stream) {
  const float* x     = (const float*)d_in[0];
  const float* H     = (const float*)d_in[1];
  const float* theta = (const float*)d_in[2];
  const float* bias  = (const float*)d_in[3];

  // ws (bytes): xtT 2MB | p_he 8MB | heT 1MB | deg_e_part 128KB | q 16MB |
  //             deg_n_part 256KB | Hbits 4MB   (~31.4 MB)
  char* ws = (char*)d_ws;
  unsigned short* xtT       = (unsigned short*)ws;
  float* p_he               = (float*)(ws + 2097152);
  unsigned short* heT       = (unsigned short*)(ws + 10485760);
  float* deg_e_part         = (float*)(ws + 11534336);
  float* q                  = (float*)(ws + 11665408);
  float* deg_n_part         = (float*)(ws + 28442624);
  unsigned long long* Hbits = (unsigned long long*)(ws + 28704768);

  k_transform<<<256, 256, 0, stream>>>(x, theta, xtT);
  k_edge<<<512, 256, 0, stream>>>(xtT, H, p_he, deg_e_part, Hbits);
  k_henorm<<<512, 256, 0, stream>>>(p_he, deg_e_part, heT);
  k_node<<<1024, 256, 0, stream>>>(Hbits, heT, q, deg_n_part);
  k_final<<<1024, 256, 0, stream>>>(q, deg_n_part, bias, (float*)d_out);
}